// Round 2
// baseline (29.695 us; speedup 1.0000x reference)
//
#include <hip/hip_runtime.h>

// MaxIndexLinearTraining: per-group (q=4) softmax then weighted sum with [1,2,3,4].
// Input: (4096, 8192) f32 -> 8,388,608 groups of 4 consecutive floats.
// Output: 8,388,608 f32.
// Memory-bound: 16B read + 4B write per group. Roofline ~26.6 us @ 6.3 TB/s.

__device__ __forceinline__ float soft_argmax4(float4 v) {
    float m  = fmaxf(fmaxf(v.x, v.y), fmaxf(v.z, v.w));
    float e0 = __expf(v.x - m);
    float e1 = __expf(v.y - m);
    float e2 = __expf(v.z - m);
    float e3 = __expf(v.w - m);
    float denom = e0 + e1 + e2 + e3;
    float num   = fmaf(4.f, e3, fmaf(3.f, e2, fmaf(2.f, e1, e0)));
    return num / denom;
}

__global__ __launch_bounds__(256) void soft_argmax_q4_kernel(
    const float4* __restrict__ in,
    float* __restrict__ out,
    int n_groups)
{
    int idx    = blockIdx.x * blockDim.x + threadIdx.x;
    int stride = gridDim.x * blockDim.x;

    // Unroll x2: two independent float4 loads in flight per iteration.
    int g = idx;
    for (; g + stride < n_groups; g += 2 * stride) {
        float4 va = in[g];
        float4 vb = in[g + stride];
        float ra = soft_argmax4(va);
        float rb = soft_argmax4(vb);
        // Output is never re-read on device: bypass caches, keep L2/L3 for input.
        __builtin_nontemporal_store(ra, &out[g]);
        __builtin_nontemporal_store(rb, &out[g + stride]);
    }
    if (g < n_groups) {
        __builtin_nontemporal_store(soft_argmax4(in[g]), &out[g]);
    }
}

extern "C" void kernel_launch(void* const* d_in, const int* in_sizes, int n_in,
                              void* d_out, int out_size, void* d_ws, size_t ws_size,
                              hipStream_t stream) {
    (void)n_in; (void)d_ws; (void)ws_size;
    const float4* in = (const float4*)d_in[0];
    float* out = (float*)d_out;

    const int n_groups = out_size;                 // 8,388,608
    const int block = 256;
    int grid = (n_groups + block - 1) / block;
    if (grid > 4096) grid = 4096;                  // 1,048,576 threads -> 8 groups each

    soft_argmax_q4_kernel<<<grid, block, 0, stream>>>(in, out, n_groups);
}